// Round 2
// 1739.926 us; speedup vs baseline: 2.5586x; 2.5586x over previous
//
#include <hip/hip_runtime.h>

#define FDIM 128

// ============================================================================
// CSR-based segment sum.
// Old path did 256M device-scope 4B float atomicAdds -> 4.1 GB of HBM RMW
// write traffic (16B billed per atomic), atomic-throughput bound at 1.38 TB/s.
// New path: histogram (2M int atomics) -> exclusive scan -> permutation array
// (2M int atomics) -> gather: one wave per segment reads its node rows
// (512B coalesced each), accumulates in registers, writes pooled once.
// Ideal traffic ~1.06 GB total, no float atomics, no pooled memset.
// ============================================================================

__global__ __launch_bounds__(256) void hist_kernel(
    const int* __restrict__ seg, int* __restrict__ count, int N)
{
    int i = blockIdx.x * 256 + threadIdx.x;
    int stride = gridDim.x * 256;
    for (; i < N; i += stride)
        atomicAdd(&count[seg[i]], 1);
}

// Single-block exclusive scan over G counts (G ~ 50K -> 49 tiles of 1024).
// Writes offsets[0..G] and a working copy (cursor) for the scatter pass.
__global__ __launch_bounds__(1024) void scan_kernel(
    const int* __restrict__ count, int* __restrict__ offsets,
    int* __restrict__ cursor, int G)
{
    __shared__ int sm[1024];
    __shared__ int carry;
    if (threadIdx.x == 0) carry = 0;
    __syncthreads();

    for (int base = 0; base < G; base += 1024) {
        int i = base + (int)threadIdx.x;
        int v = (i < G) ? count[i] : 0;
        sm[threadIdx.x] = v;
        __syncthreads();
        // Hillis-Steele inclusive scan (read, sync, write, sync)
        for (int off = 1; off < 1024; off <<= 1) {
            int t = (threadIdx.x >= (unsigned)off) ? sm[threadIdx.x - off] : 0;
            __syncthreads();
            sm[threadIdx.x] += t;
            __syncthreads();
        }
        int incl = sm[threadIdx.x];
        int excl = incl - v + carry;            // all threads read carry here
        if (i < G) { offsets[i] = excl; cursor[i] = excl; }
        __syncthreads();                        // everyone done reading carry
        if (threadIdx.x == 1023) carry += sm[1023];
        __syncthreads();
    }
    if (threadIdx.x == 0) offsets[G] = carry;   // == N
}

__global__ __launch_bounds__(256) void build_perm(
    const int* __restrict__ seg, int* __restrict__ cursor,
    int* __restrict__ perm, int N)
{
    int i = blockIdx.x * 256 + threadIdx.x;
    int stride = gridDim.x * 256;
    for (; i < N; i += stride) {
        int s = seg[i];
        int p = atomicAdd(&cursor[s], 1);
        perm[p] = i;
    }
}

// One wave (64 lanes) per segment. Each lane owns a float2 column slice of the
// 128-float row (8B/lane * 64 = 512B coalesced per row read). Register
// accumulation; single coalesced write of the pooled row. Unroll-4 over the
// node list to keep 4 row loads in flight past the dependent perm[] load.
__global__ __launch_bounds__(256) void gather_sum(
    const float* __restrict__ h, const int* __restrict__ perm,
    const int* __restrict__ offsets, float* __restrict__ pooled, int G)
{
    int wid  = (blockIdx.x * 256 + threadIdx.x) >> 6;  // wave id == segment id
    int lane = threadIdx.x & 63;
    if (wid >= G) return;

    int beg = offsets[wid];
    int end = offsets[wid + 1];
    float2 acc = make_float2(0.f, 0.f);

    int t = beg;
    for (; t + 4 <= end; t += 4) {
        int n0 = perm[t + 0];
        int n1 = perm[t + 1];
        int n2 = perm[t + 2];
        int n3 = perm[t + 3];
        float2 v0 = *((const float2*)(h + (size_t)n0 * FDIM) + lane);
        float2 v1 = *((const float2*)(h + (size_t)n1 * FDIM) + lane);
        float2 v2 = *((const float2*)(h + (size_t)n2 * FDIM) + lane);
        float2 v3 = *((const float2*)(h + (size_t)n3 * FDIM) + lane);
        acc.x += v0.x + v1.x + v2.x + v3.x;
        acc.y += v0.y + v1.y + v2.y + v3.y;
    }
    for (; t < end; ++t) {
        int n = perm[t];
        float2 v = *((const float2*)(h + (size_t)n * FDIM) + lane);
        acc.x += v.x;
        acc.y += v.y;
    }
    reinterpret_cast<float2*>(pooled + (size_t)wid * FDIM)[lane] = acc;
}

// ----------------------------------------------------------------------------
// Fallback (old) scatter-atomic path, used only if the workspace is too small
// for the CSR buffers. Kept verbatim from the verified kernel.
// ----------------------------------------------------------------------------
__global__ __launch_bounds__(256) void seg_sum_kernel(
    const float* __restrict__ h, const int* __restrict__ seg,
    float* __restrict__ pooled, int n4)
{
    int gid = blockIdx.x * 256 + threadIdx.x;
    if (gid >= n4) return;
    int node = gid >> 5;
    int q    = gid & 31;
    float4 v = reinterpret_cast<const float4*>(h)[(size_t)node * 32 + q];
    int s = seg[node];
    float* dst = pooled + (size_t)s * FDIM + q * 4;
    atomicAdd(dst + 0, v.x);
    atomicAdd(dst + 1, v.y);
    atomicAdd(dst + 2, v.z);
    atomicAdd(dst + 3, v.w);
}

// ============================================================================
// Phase 2: y[g] = tanh(pooled[g,:] @ W1 + b1) @ W2 + b2
// Same verified structure as before; two low-risk changes:
//  - unroll 8 -> 4 on the inner loop (8 kept ~128 W-floats live -> suspected
//    VGPR spills; this kernel measured ~1100us vs ~100us arithmetic model)
//  - float4-vectorized W1 -> LDS staging
// ============================================================================
__global__ __launch_bounds__(256) void mlp_kernel(
    const float* __restrict__ pooled,
    const float* __restrict__ W1, const float* __restrict__ b1,
    const float* __restrict__ W2, const float* __restrict__ b2,
    float* __restrict__ out, int G)
{
    __shared__ float w1s[FDIM * FDIM];  // 64 KB
    {
        const float4* src = reinterpret_cast<const float4*>(W1);
        float4* dst = reinterpret_cast<float4*>(w1s);
        for (int i = threadIdx.x; i < FDIM * FDIM / 4; i += 256)
            dst[i] = src[i];
    }

    int grp  = threadIdx.x >> 5;
    int lane = threadIdx.x & 31;
    float  b2v = b2[0];
    float4 bb  = reinterpret_cast<const float4*>(b1)[lane];
    float4 ww  = reinterpret_cast<const float4*>(W2)[lane];
    __syncthreads();

    const float4* wrow = reinterpret_cast<const float4*>(w1s);

    for (int gbase = blockIdx.x * 8; gbase < G; gbase += gridDim.x * 8) {
        int g = gbase + grp;
        float4 myrow = make_float4(0.f, 0.f, 0.f, 0.f);
        if (g < G)
            myrow = reinterpret_cast<const float4*>(pooled + (size_t)g * FDIM)[lane];

        float4 acc = make_float4(0.f, 0.f, 0.f, 0.f);
        #pragma unroll 4
        for (int l = 0; l < 32; ++l) {
            float vx = __shfl(myrow.x, l, 32);
            float vy = __shfl(myrow.y, l, 32);
            float vz = __shfl(myrow.z, l, 32);
            float vw = __shfl(myrow.w, l, 32);
            float4 w0 = wrow[(l * 4 + 0) * 32 + lane];
            float4 w1 = wrow[(l * 4 + 1) * 32 + lane];
            float4 w2 = wrow[(l * 4 + 2) * 32 + lane];
            float4 w3 = wrow[(l * 4 + 3) * 32 + lane];
            acc.x = fmaf(vx, w0.x, acc.x); acc.y = fmaf(vx, w0.y, acc.y);
            acc.z = fmaf(vx, w0.z, acc.z); acc.w = fmaf(vx, w0.w, acc.w);
            acc.x = fmaf(vy, w1.x, acc.x); acc.y = fmaf(vy, w1.y, acc.y);
            acc.z = fmaf(vy, w1.z, acc.z); acc.w = fmaf(vy, w1.w, acc.w);
            acc.x = fmaf(vz, w2.x, acc.x); acc.y = fmaf(vz, w2.y, acc.y);
            acc.z = fmaf(vz, w2.z, acc.z); acc.w = fmaf(vz, w2.w, acc.w);
            acc.x = fmaf(vw, w3.x, acc.x); acc.y = fmaf(vw, w3.y, acc.y);
            acc.z = fmaf(vw, w3.z, acc.z); acc.w = fmaf(vw, w3.w, acc.w);
        }

        float t = tanhf(acc.x + bb.x) * ww.x
                + tanhf(acc.y + bb.y) * ww.y
                + tanhf(acc.z + bb.z) * ww.z
                + tanhf(acc.w + bb.w) * ww.w;

        for (int off = 16; off > 0; off >>= 1)
            t += __shfl_down(t, off, 32);

        if (lane == 0 && g < G) out[g] = t + b2v;
    }
}

extern "C" void kernel_launch(void* const* d_in, const int* in_sizes, int n_in,
                              void* d_out, int out_size, void* d_ws, size_t ws_size,
                              hipStream_t stream) {
    const float* h   = (const float*)d_in[0];
    const int*   seg = (const int*)d_in[1];
    // d_in[2] = num_graphs scalar (device mem) — G derived from out_size instead
    const float* W1  = (const float*)d_in[3];
    const float* b1  = (const float*)d_in[4];
    const float* W2  = (const float*)d_in[5];
    const float* b2  = (const float*)d_in[6];
    float* out = (float*)d_out;

    int N = in_sizes[0] / FDIM;   // 2,000,000
    int G = out_size;             // 50,000 (OUT=1)

    // Workspace layout
    float* pooled = (float*)d_ws;                       // G*128 floats (25.6 MB)
    char* p = (char*)d_ws + (size_t)G * FDIM * sizeof(float);
    int* count   = (int*)p;  p += (size_t)G * sizeof(int);
    int* offsets = (int*)p;  p += (size_t)(G + 1) * sizeof(int);
    int* cursor  = (int*)p;  p += (size_t)G * sizeof(int);
    int* perm    = (int*)p;  p += (size_t)N * sizeof(int);
    size_t needed = (size_t)(p - (char*)d_ws);

    if (ws_size >= needed) {
        // CSR path: no pooled memset needed (gather writes every row)
        hipMemsetAsync(count, 0, (size_t)G * sizeof(int), stream);
        hist_kernel<<<2048, 256, 0, stream>>>(seg, count, N);
        scan_kernel<<<1, 1024, 0, stream>>>(count, offsets, cursor, G);
        build_perm<<<2048, 256, 0, stream>>>(seg, cursor, perm, N);
        int gblocks = (G * 64 + 255) / 256;   // one wave per segment
        gather_sum<<<gblocks, 256, 0, stream>>>(h, perm, offsets, pooled, G);
    } else {
        // Fallback: original atomic scatter
        hipMemsetAsync(pooled, 0, (size_t)G * FDIM * sizeof(float), stream);
        int n4 = N * 32;
        seg_sum_kernel<<<(n4 + 255) / 256, 256, 0, stream>>>(h, seg, pooled, n4);
    }

    mlp_kernel<<<1024, 256, 0, stream>>>(pooled, W1, b1, W2, b2, out, G);
}